// Round 3
// baseline (208.781 us; speedup 1.0000x reference)
//
#include <hip/hip_runtime.h>
#include <hip/hip_bf16.h>

typedef __attribute__((ext_vector_type(4))) short short4v;
typedef __attribute__((ext_vector_type(8))) short short8v;
typedef __attribute__((ext_vector_type(4))) float float4v;
typedef __attribute__((ext_vector_type(2))) unsigned int uint2v;
typedef __attribute__((ext_vector_type(4))) unsigned int uint4v;

#define NTOK 2048      // n = T*S
#define MROWS 4096     // B*n
#define DMODEL 512
#define NINNER 1024
#define DH 64
#define HH 16
#define LOG2E 1.4426950408889634f

__device__ __forceinline__ unsigned short b2s(float f) {
    __hip_bfloat16 h = __float2bfloat16(f);
    return __builtin_bit_cast(unsigned short, h);
}

__device__ __forceinline__ float4v mfma32(short8v a, short8v b, float4v c) {
    return __builtin_amdgcn_mfma_f32_16x16x32_bf16(a, b, c, 0, 0, 0);
}

__device__ __forceinline__ void gld16(const void* g, void* l) {
    __builtin_amdgcn_global_load_lds((const __attribute__((address_space(1))) void*)g,
                                     (__attribute__((address_space(3))) void*)l, 16, 0, 0);
}

// ---- x,y + pos_emb -> bf16 ----
__global__ void k_prep(const float* __restrict__ x, const float* __restrict__ y,
                       const float* __restrict__ pe,
                       unsigned short* __restrict__ xpb, unsigned short* __restrict__ ypb) {
    int idx = blockIdx.x * blockDim.x + threadIdx.x;
    int e0 = idx * 4;
    if (e0 >= MROWS * DMODEL) return;
    int row = e0 >> 9, col = e0 & 511;
    int t = (row & (NTOK - 1)) >> 7;
    const float4v xv = *(const float4v*)(x + e0);
    const float4v yv = *(const float4v*)(y + e0);
    const float4v pv = *(const float4v*)(pe + t * DMODEL + col);
    short4v xo, yo;
#pragma unroll
    for (int i = 0; i < 4; ++i) {
        xo[i] = (short)b2s(xv[i] + pv[i]);
        yo[i] = (short)b2s(yv[i] + pv[i]);
    }
    *(short4v*)(xpb + e0) = xo;
    *(short4v*)(ypb + e0) = yo;
}

// ---- fused: 4 weight transposes (f32 -> bf16, [K][N] -> [N][K]) + RoPE trig tables ----
__global__ void k_misc(const float* __restrict__ Wq, const float* __restrict__ Wk,
                       const float* __restrict__ Wv, const float* __restrict__ Wo,
                       unsigned short* __restrict__ wqt, unsigned short* __restrict__ wkt,
                       unsigned short* __restrict__ wvt, unsigned short* __restrict__ wot,
                       float* __restrict__ ctab, float* __restrict__ stab) {
    int blk = blockIdx.x;
    if (blk < 6144) {  // wq/wk/wv: [512][1024] -> [1024][512]
        int which = blk >> 11;
        int idx = (blk & 2047) * 256 + threadIdx.x;
        const float* W = (which == 0) ? Wq : (which == 1) ? Wk : Wv;
        unsigned short* Wt = (which == 0) ? wqt : (which == 1) ? wkt : wvt;
        int n = idx & 1023, k = idx >> 10;
        Wt[n * 512 + k] = b2s(W[idx]);
    } else if (blk < 8192) {  // wo: [1024][512] -> [512][1024]
        int idx = (blk - 6144) * 256 + threadIdx.x;
        int n = idx & 511, k = idx >> 9;
        wot[n * 1024 + k] = b2s(Wo[idx]);
    } else {  // rope tables [2048][32]
        int idx = (blk - 8192) * 256 + threadIdx.x;
        int p = idx >> 5, j = idx & 31;
        float invf = powf(10000.0f, -(float)(2 * j) * (1.0f / 64.0f));
        float f = (float)p * invf;
        ctab[idx] = cosf(f);
        stab[idx] = sinf(f);
    }
}

// ---- bf16 MFMA GEMM, fragment-order LDS + global_load_lds + double buffer ----
// C[M][N] = A[M][K] @ Bt[N][K]^T. tile 128x64, BK=32, 4 waves.
// EPI: 0 = f32 +bias (row-major), 1 = RoPE -> bf16 [B,H,n,64] (*scale), 2 = V^T -> bf16 [B,H,64,n]
template <int EPI>
__global__ __launch_bounds__(256) void k_gemm(const unsigned short* __restrict__ A,
                                              const unsigned short* __restrict__ Bt,
                                              void* __restrict__ Cv,
                                              const float* __restrict__ bias,
                                              const float* __restrict__ ctab,
                                              const float* __restrict__ stab,
                                              float scale, int M, int N, int K) {
    __shared__ unsigned short Ab[2][4096];  // 8 frags x (64 lanes x 8 shorts)
    __shared__ unsigned short Bb[2][2048];  // 4 frags
    const int tid = threadIdx.x;
    const int w = tid >> 6, l = tid & 63, l16 = l & 15, g = l >> 4;
    const int m0 = blockIdx.y * 128, n0 = blockIdx.x * 64;
    float4v acc[2][4];
#pragma unroll
    for (int i = 0; i < 2; ++i)
#pragma unroll
        for (int j = 0; j < 4; ++j) acc[i][j] = (float4v){0.f, 0.f, 0.f, 0.f};

    const int nstep = K >> 5;
    auto stage = [&](int t, int buf) {
        int k0 = t * 32;
#pragma unroll
        for (int s = 0; s < 2; ++s) {
            int fi = s * 4 + w;
            gld16(A + (size_t)(m0 + fi * 16 + l16) * K + k0 + g * 8, &Ab[buf][fi * 512]);
        }
        gld16(Bt + (size_t)(n0 + w * 16 + l16) * K + k0 + g * 8, &Bb[buf][w * 512]);
    };

    stage(0, 0);
    __syncthreads();
    for (int t = 0; t < nstep; ++t) {
        const int cur = t & 1;
        if (t + 1 < nstep) stage(t + 1, cur ^ 1);
        short8v af[2], bf[4];
#pragma unroll
        for (int mi = 0; mi < 2; ++mi)
            af[mi] = *(const short8v*)&Ab[cur][(w * 2 + mi) * 512 + l * 8];
#pragma unroll
        for (int nj = 0; nj < 4; ++nj)
            bf[nj] = *(const short8v*)&Bb[cur][nj * 512 + l * 8];
        __builtin_amdgcn_s_setprio(1);
#pragma unroll
        for (int mi = 0; mi < 2; ++mi)
#pragma unroll
            for (int nj = 0; nj < 4; ++nj)
                acc[mi][nj] = mfma32(af[mi], bf[nj], acc[mi][nj]);
        __builtin_amdgcn_s_setprio(0);
        __syncthreads();  // drains vmcnt (prefetch) + lgkmcnt before buffer swap
    }

    if (EPI == 0) {
#pragma unroll
        for (int mi = 0; mi < 2; ++mi)
#pragma unroll
            for (int nj = 0; nj < 4; ++nj) {
                int col = n0 + nj * 16 + l16;
                float bv = bias ? bias[col] : 0.0f;
#pragma unroll
                for (int r = 0; r < 4; ++r) {
                    int row = m0 + w * 32 + mi * 16 + g * 4 + r;
                    ((float*)Cv)[(size_t)row * N + col] = acc[mi][nj][r] + bv;
                }
            }
    } else if (EPI == 1) {  // RoPE: cols n0..n0+63 = one head; pairs (j, j+32) in-lane
        const int hh = n0 >> 6;
        unsigned short* out = (unsigned short*)Cv;
#pragma unroll
        for (int mi = 0; mi < 2; ++mi)
#pragma unroll
            for (int r = 0; r < 4; ++r) {
                int row = m0 + w * 32 + mi * 16 + g * 4 + r;
                int b = row >> 11, pos = row & (NTOK - 1);
                const float* cr = ctab + pos * 32;
                const float* sr = stab + pos * 32;
                unsigned short* ob = out + (size_t)((b * HH + hh) * NTOK + pos) * DH;
#pragma unroll
                for (int nj = 0; nj < 2; ++nj) {
                    int j = nj * 16 + l16;
                    float c = cr[j], s = sr[j];
                    float v1 = acc[mi][nj][r], v2 = acc[mi][nj + 2][r];
                    ob[j] = b2s((v1 * c - v2 * s) * scale);
                    ob[j + 32] = b2s((v2 * c + v1 * s) * scale);
                }
            }
    } else {  // EPI == 2: V^T layout [B,H,64,n]
        const int hh = n0 >> 6;
        unsigned short* out = (unsigned short*)Cv;
#pragma unroll
        for (int mi = 0; mi < 2; ++mi)
#pragma unroll
            for (int nj = 0; nj < 4; ++nj) {
                int d = nj * 16 + l16;
                int row0 = m0 + w * 32 + mi * 16 + g * 4;
                int b = row0 >> 11, pos0 = row0 & (NTOK - 1);
                short4v o;
#pragma unroll
                for (int r = 0; r < 4; ++r) o[r] = (short)b2s(acc[mi][nj][r]);
                *(short4v*)(out + (size_t)((b * HH + hh) * DH + d) * NTOK + pos0) = o;
            }
    }
}

// ---- fused masked flash attention v3: one independent wave per 32-row q-tile ----
// grid: B*H*T*4 = 2048 blocks x 64 thr. No LDS, no barriers. Mask -> ballot bitmask.
// S^T = K@Q^T; O^T = V^T@P^T (P stays in registers, frag-order match => no shuffles).
// XCD chunk swizzle: 256 consecutive units per XCD = 4 heads = 2MB K/V -> L2-resident.
__global__ __launch_bounds__(64) void k_attn(const unsigned short* __restrict__ qh,
                                             const unsigned short* __restrict__ kh,
                                             const unsigned short* __restrict__ vt,
                                             const int* __restrict__ tmask,
                                             unsigned short* __restrict__ otmp) {
    const int blk = blockIdx.x;
    const int u = (blk & 7) * 256 + (blk >> 3);  // bijective XCD chunking (2048 % 8 == 0)
    const int wq = u & 3, ti = (u >> 2) & 15, h = (u >> 6) & 15, b = u >> 10;
    const int l = threadIdx.x & 63, l16 = l & 15, g = l >> 4;
    const unsigned short* qb = qh + (size_t)((b * HH + h) * NTOK) * DH;
    const unsigned short* kb = kh + (size_t)((b * HH + h) * NTOK) * DH;
    const unsigned short* vb = vt + (size_t)((b * HH + h) * DH) * NTOK;
    const int q0 = ti * 128 + wq * 32;

    int mv = (l < 16) ? tmask[(b * 16 + ti) * 16 + l] : 0;
    unsigned long long mb = __ballot(mv != 0);

    short8v qf[2][2];
#pragma unroll
    for (int nq = 0; nq < 2; ++nq)
#pragma unroll
        for (int c = 0; c < 2; ++c)
            qf[nq][c] = *(const short8v*)(qb + (size_t)(q0 + nq * 16 + l16) * DH + c * 32 + g * 8);

    float4v oacc[4][2];
#pragma unroll
    for (int i = 0; i < 4; ++i)
#pragma unroll
        for (int j = 0; j < 2; ++j) oacc[i][j] = (float4v){0.f, 0.f, 0.f, 0.f};
    float mx[2] = {-1e30f, -1e30f}, lrow[2] = {0.f, 0.f};

    while (mb) {
        const int tj = __builtin_ctzll(mb);
        mb &= mb - 1;
        const int k0 = tj * 128;
        // ---- K frags (die after QK) ----
        short8v kf[8][2];
#pragma unroll
        for (int jk = 0; jk < 8; ++jk)
#pragma unroll
            for (int c = 0; c < 2; ++c)
                kf[jk][c] = *(const short8v*)(kb + (size_t)(k0 + jk * 16 + l16) * DH + c * 32 + g * 8);
        // ---- QK^T ----
        float4v sacc[8][2];
#pragma unroll
        for (int jk = 0; jk < 8; ++jk)
#pragma unroll
            for (int nq = 0; nq < 2; ++nq) sacc[jk][nq] = (float4v){0.f, 0.f, 0.f, 0.f};
        __builtin_amdgcn_s_setprio(1);
#pragma unroll
        for (int jk = 0; jk < 8; ++jk)
#pragma unroll
            for (int nq = 0; nq < 2; ++nq) {
                sacc[jk][nq] = mfma32(kf[jk][0], qf[nq][0], sacc[jk][nq]);
                sacc[jk][nq] = mfma32(kf[jk][1], qf[nq][1], sacc[jk][nq]);
            }
        __builtin_amdgcn_s_setprio(0);
        // ---- V frags (issued here; softmax covers the latency) ----
        short8v vf[4][4];
#pragma unroll
        for (int md = 0; md < 4; ++md)
#pragma unroll
            for (int cc = 0; cc < 4; ++cc) {
                const unsigned short* ga =
                    vb + (size_t)(md * 16 + l16) * NTOK + k0 + cc * 32 + g * 4;
                uint2v lo = *(const uint2v*)ga;
                uint2v hi = *(const uint2v*)(ga + 16);
                uint4v m4 = {lo[0], lo[1], hi[0], hi[1]};
                vf[md][cc] = __builtin_bit_cast(short8v, m4);
            }
        // ---- online softmax (base-2; log2e folded into q) with defer-max ----
        short8v pf[4][2];
#pragma unroll
        for (int nq = 0; nq < 2; ++nq) {
            float tm = -1e30f;
#pragma unroll
            for (int jk = 0; jk < 8; ++jk) {
                float4v s4 = sacc[jk][nq];
                tm = fmaxf(tm, fmaxf(fmaxf(s4[0], s4[1]), fmaxf(s4[2], s4[3])));
            }
            tm = fmaxf(tm, __shfl_xor(tm, 16));
            tm = fmaxf(tm, __shfl_xor(tm, 32));
            if (!__all(tm <= mx[nq] + 8.0f)) {  // defer-max: p bounded by 2^8
                float mnew = fmaxf(mx[nq], tm);
                float alpha = exp2f(mx[nq] - mnew);
                lrow[nq] *= alpha;
#pragma unroll
                for (int md = 0; md < 4; ++md)
#pragma unroll
                    for (int r = 0; r < 4; ++r) oacc[md][nq][r] *= alpha;
                mx[nq] = mnew;
            }
            const float m0 = mx[nq];
            float4v tsv = {0.f, 0.f, 0.f, 0.f};
#pragma unroll
            for (int cc = 0; cc < 4; ++cc) {
                float p[8];
#pragma unroll
                for (int r = 0; r < 4; ++r) {
                    p[r] = exp2f(sacc[2 * cc][nq][r] - m0);
                    p[r + 4] = exp2f(sacc[2 * cc + 1][nq][r] - m0);
                }
                short8v pv;
#pragma unroll
                for (int r = 0; r < 4; ++r) {
                    tsv[r] += p[r] + p[r + 4];
                    pv[r] = (short)b2s(p[r]);
                    pv[r + 4] = (short)b2s(p[r + 4]);
                }
                pf[cc][nq] = pv;
            }
            float ts = (tsv[0] + tsv[1]) + (tsv[2] + tsv[3]);
            ts += __shfl_xor(ts, 16);
            ts += __shfl_xor(ts, 32);
            lrow[nq] += ts;
        }
        // ---- O^T += V^T @ P^T ----
        __builtin_amdgcn_s_setprio(1);
#pragma unroll
        for (int md = 0; md < 4; ++md)
#pragma unroll
            for (int cc = 0; cc < 4; ++cc)
#pragma unroll
                for (int nq = 0; nq < 2; ++nq)
                    oacc[md][nq] = mfma32(vf[md][cc], pf[cc][nq], oacc[md][nq]);
        __builtin_amdgcn_s_setprio(0);
    }
#pragma unroll
    for (int nq = 0; nq < 2; ++nq) {
        float inv = lrow[nq] > 0.f ? 1.0f / lrow[nq] : 0.f;
        int q = q0 + nq * 16 + l16;
#pragma unroll
        for (int md = 0; md < 4; ++md) {
            short4v o;
#pragma unroll
            for (int r = 0; r < 4; ++r) o[r] = (short)b2s(oacc[md][nq][r] * inv);
            *(short4v*)(otmp + (size_t)(b * NTOK + q) * NINNER + h * DH + md * 16 + g * 4) = o;
        }
    }
}

// ---- gate: out = proj * sigmoid(proj @ gate_w + gate_b) ----
__global__ __launch_bounds__(256) void k_gate(const float* __restrict__ proj,
                                              const float* __restrict__ gw,
                                              const float* __restrict__ gb,
                                              float* __restrict__ out) {
    int row = blockIdx.x * 4 + (threadIdx.x >> 6);
    int l = threadIdx.x & 63;
    const float* pr = proj + (size_t)row * DMODEL;
    float acc = 0.f;
#pragma unroll
    for (int c = 0; c < DMODEL; c += 64) acc += pr[c + l] * gw[c + l];
#pragma unroll
    for (int off = 32; off > 0; off >>= 1) acc += __shfl_xor(acc, off);
    float gt = 1.0f / (1.0f + __expf(-(acc + gb[0])));
    float* orow = out + (size_t)row * DMODEL;
#pragma unroll
    for (int c = 0; c < DMODEL; c += 64) orow[c + l] = pr[c + l] * gt;
}

extern "C" void kernel_launch(void* const* d_in, const int* in_sizes, int n_in,
                              void* d_out, int out_size, void* d_ws, size_t ws_size,
                              hipStream_t stream) {
    (void)in_sizes; (void)n_in; (void)out_size; (void)ws_size;
    const float* x = (const float*)d_in[0];
    const float* y = (const float*)d_in[1];
    const int* tmask = (const int*)d_in[2];
    const float* Wq = (const float*)d_in[3];
    const float* Wk = (const float*)d_in[4];
    const float* Wv = (const float*)d_in[5];
    const float* Wo = (const float*)d_in[6];
    const float* bo = (const float*)d_in[7];
    const float* pe = (const float*)d_in[8];
    const float* gw = (const float*)d_in[9];
    const float* gb = (const float*)d_in[10];

    char* ws = (char*)d_ws;
    const size_t MB = 1u << 20;
    unsigned short* xpb = (unsigned short*)(ws + 0);         // 4MB
    unsigned short* ypb = (unsigned short*)(ws + 4 * MB);    // 4MB
    unsigned short* wqt = (unsigned short*)(ws + 8 * MB);    // 1MB each
    unsigned short* wkt = (unsigned short*)(ws + 9 * MB);
    unsigned short* wvt = (unsigned short*)(ws + 10 * MB);
    unsigned short* wot = (unsigned short*)(ws + 11 * MB);
    unsigned short* qh  = (unsigned short*)(ws + 12 * MB);   // 8MB  [B,H,n,64] bf16
    unsigned short* kh  = (unsigned short*)(ws + 20 * MB);   // 8MB
    unsigned short* vt  = (unsigned short*)(ws + 28 * MB);   // 8MB  [B,H,64,n] bf16
    unsigned short* otm = (unsigned short*)(ws + 36 * MB);   // 8MB  [B*n,1024] bf16
    float* proj = (float*)(ws + 44 * MB);                    // 8MB  f32
    float* ct = (float*)(ws + 52 * MB);                      // 256KB
    float* st = (float*)(ws + 52 * MB + 256 * 1024);         // 256KB
    float* outp = (float*)d_out;

    k_prep<<<2048, 256, 0, stream>>>(x, y, pe, xpb, ypb);
    k_misc<<<8448, 256, 0, stream>>>(Wq, Wk, Wv, Wo, wqt, wkt, wvt, wot, ct, st);
    // q,k from x (bug-compatible with reference); v from y.
    k_gemm<1><<<dim3(16, 32), 256, 0, stream>>>(xpb, wqt, qh, nullptr, ct, st,
                                                0.125f * LOG2E, 4096, 1024, 512);
    k_gemm<1><<<dim3(16, 32), 256, 0, stream>>>(xpb, wkt, kh, nullptr, ct, st,
                                                1.0f, 4096, 1024, 512);
    k_gemm<2><<<dim3(16, 32), 256, 0, stream>>>(ypb, wvt, vt, nullptr, nullptr, nullptr,
                                                1.0f, 4096, 1024, 512);
    k_attn<<<2048, 64, 0, stream>>>(qh, kh, vt, tmask, otm);
    k_gemm<0><<<dim3(8, 32), 256, 0, stream>>>(otm, wot, proj, bo, nullptr, nullptr,
                                               1.0f, 4096, 512, 1024);
    k_gate<<<1024, 256, 0, stream>>>(proj, gw, gb, outp);
}

// Round 4
// 150.387 us; speedup vs baseline: 1.3883x; 1.3883x over previous
//
#include <hip/hip_runtime.h>
#include <hip/hip_bf16.h>

typedef __attribute__((ext_vector_type(4))) short short4v;
typedef __attribute__((ext_vector_type(8))) short short8v;
typedef __attribute__((ext_vector_type(4))) float float4v;
typedef __attribute__((ext_vector_type(2))) unsigned int uint2v;
typedef __attribute__((ext_vector_type(4))) unsigned int uint4v;

#define NTOK 2048      // n = T*S
#define MROWS 4096     // B*n
#define DMODEL 512
#define NINNER 1024
#define DH 64
#define HH 16
#define LOG2E 1.4426950408889634f

__device__ __forceinline__ unsigned short b2s(float f) {
    __hip_bfloat16 h = __float2bfloat16(f);
    return __builtin_bit_cast(unsigned short, h);
}

__device__ __forceinline__ float4v mfma32(short8v a, short8v b, float4v c) {
    return __builtin_amdgcn_mfma_f32_16x16x32_bf16(a, b, c, 0, 0, 0);
}

__device__ __forceinline__ void gld16(const void* g, void* l) {
    __builtin_amdgcn_global_load_lds((const __attribute__((address_space(1))) void*)g,
                                     (__attribute__((address_space(3))) void*)l, 16, 0, 0);
}

// ---- fused prologue: x,y+pos_emb->bf16 | weight transposes | rope tables ----
__global__ void k_pre(const float* __restrict__ x, const float* __restrict__ y,
                      const float* __restrict__ pe,
                      unsigned short* __restrict__ xpb, unsigned short* __restrict__ ypb,
                      const float* __restrict__ Wq, const float* __restrict__ Wk,
                      const float* __restrict__ Wv, const float* __restrict__ Wo,
                      unsigned short* __restrict__ wqkt, unsigned short* __restrict__ wvt,
                      unsigned short* __restrict__ wot,
                      float* __restrict__ ctab, float* __restrict__ stab) {
    int blk = blockIdx.x;
    if (blk < 2048) {  // prep: x,y + pos_emb -> bf16
        int e0 = (blk * 256 + threadIdx.x) * 4;
        int row = e0 >> 9, col = e0 & 511;
        int t = (row & (NTOK - 1)) >> 7;
        const float4v xv = *(const float4v*)(x + e0);
        const float4v yv = *(const float4v*)(y + e0);
        const float4v pv = *(const float4v*)(pe + t * DMODEL + col);
        short4v xo, yo;
#pragma unroll
        for (int i = 0; i < 4; ++i) {
            xo[i] = (short)b2s(xv[i] + pv[i]);
            yo[i] = (short)b2s(yv[i] + pv[i]);
        }
        *(short4v*)(xpb + e0) = xo;
        *(short4v*)(ypb + e0) = yo;
    } else if (blk < 8192) {  // wq/wk/wv: [512][1024] -> [1024][512]; q,k contiguous in wqkt
        int which = (blk - 2048) >> 11;
        int idx = ((blk - 2048) & 2047) * 256 + threadIdx.x;
        const float* W = (which == 0) ? Wq : (which == 1) ? Wk : Wv;
        int n = idx & 1023, k = idx >> 10;
        unsigned short v = b2s(W[idx]);
        if (which == 0) wqkt[n * 512 + k] = v;
        else if (which == 1) wqkt[(1024 + n) * 512 + k] = v;
        else wvt[n * 512 + k] = v;
    } else if (blk < 10240) {  // wo: [1024][512] -> [512][1024]
        int idx = (blk - 8192) * 256 + threadIdx.x;
        int n = idx & 511, k = idx >> 9;
        wot[n * 1024 + k] = b2s(Wo[idx]);
    } else {  // rope tables [2048][32]
        int idx = (blk - 10240) * 256 + threadIdx.x;
        int p = idx >> 5, j = idx & 31;
        float invf = powf(10000.0f, -(float)(2 * j) * (1.0f / 64.0f));
        float f = (float)p * invf;
        ctab[idx] = cosf(f);
        stab[idx] = sinf(f);
    }
}

// ---- bf16 MFMA GEMM, fragment-order LDS + global_load_lds + double buffer ----
// C[M][N] = A[M][K] @ Bt[N][K]^T. tile 128x64, BK=32, 4 waves.
// EPI: 0 = f32 +bias (row-major), 1 = RoPE -> bf16 [B,H,n,64]; cols<1024 -> Cv (q, *scale),
//      cols>=1024 -> Cv2 (k, *1);  2 = V^T -> bf16 [B,H,64,n]
template <int EPI>
__global__ __launch_bounds__(256) void k_gemm(const unsigned short* __restrict__ A,
                                              const unsigned short* __restrict__ Bt,
                                              void* __restrict__ Cv, void* __restrict__ Cv2,
                                              const float* __restrict__ bias,
                                              const float* __restrict__ ctab,
                                              const float* __restrict__ stab,
                                              float scale, int M, int N, int K) {
    __shared__ unsigned short Ab[2][4096];  // 8 frags x (64 lanes x 8 shorts)
    __shared__ unsigned short Bb[2][2048];  // 4 frags
    const int tid = threadIdx.x;
    const int w = tid >> 6, l = tid & 63, l16 = l & 15, g = l >> 4;
    const int m0 = blockIdx.y * 128, n0 = blockIdx.x * 64;
    float4v acc[2][4];
#pragma unroll
    for (int i = 0; i < 2; ++i)
#pragma unroll
        for (int j = 0; j < 4; ++j) acc[i][j] = (float4v){0.f, 0.f, 0.f, 0.f};

    const int nstep = K >> 5;
    auto stage = [&](int t, int buf) {
        int k0 = t * 32;
#pragma unroll
        for (int s = 0; s < 2; ++s) {
            int fi = s * 4 + w;
            gld16(A + (size_t)(m0 + fi * 16 + l16) * K + k0 + g * 8, &Ab[buf][fi * 512]);
        }
        gld16(Bt + (size_t)(n0 + w * 16 + l16) * K + k0 + g * 8, &Bb[buf][w * 512]);
    };

    stage(0, 0);
    __syncthreads();
    for (int t = 0; t < nstep; ++t) {
        const int cur = t & 1;
        if (t + 1 < nstep) stage(t + 1, cur ^ 1);
        short8v af[2], bf[4];
#pragma unroll
        for (int mi = 0; mi < 2; ++mi)
            af[mi] = *(const short8v*)&Ab[cur][(w * 2 + mi) * 512 + l * 8];
#pragma unroll
        for (int nj = 0; nj < 4; ++nj)
            bf[nj] = *(const short8v*)&Bb[cur][nj * 512 + l * 8];
        __builtin_amdgcn_s_setprio(1);
#pragma unroll
        for (int mi = 0; mi < 2; ++mi)
#pragma unroll
            for (int nj = 0; nj < 4; ++nj)
                acc[mi][nj] = mfma32(af[mi], bf[nj], acc[mi][nj]);
        __builtin_amdgcn_s_setprio(0);
        __syncthreads();  // drains vmcnt (prefetch) + lgkmcnt before buffer swap
    }

    if (EPI == 0) {
#pragma unroll
        for (int mi = 0; mi < 2; ++mi)
#pragma unroll
            for (int nj = 0; nj < 4; ++nj) {
                int col = n0 + nj * 16 + l16;
                float bv = bias ? bias[col] : 0.0f;
#pragma unroll
                for (int r = 0; r < 4; ++r) {
                    int row = m0 + w * 32 + mi * 16 + g * 4 + r;
                    ((float*)Cv)[(size_t)row * N + col] = acc[mi][nj][r] + bv;
                }
            }
    } else if (EPI == 1) {  // RoPE: cols n0..n0+63 = one head; pairs (j, j+32) in-lane
        const int hh = n0 >> 6;
        const int head = hh & 15;
        unsigned short* out = (hh < 16) ? (unsigned short*)Cv : (unsigned short*)Cv2;
        const float sc = (hh < 16) ? scale : 1.0f;
#pragma unroll
        for (int mi = 0; mi < 2; ++mi)
#pragma unroll
            for (int r = 0; r < 4; ++r) {
                int row = m0 + w * 32 + mi * 16 + g * 4 + r;
                int b = row >> 11, pos = row & (NTOK - 1);
                const float* cr = ctab + pos * 32;
                const float* sr = stab + pos * 32;
                unsigned short* ob = out + (size_t)((b * HH + head) * NTOK + pos) * DH;
#pragma unroll
                for (int nj = 0; nj < 2; ++nj) {
                    int j = nj * 16 + l16;
                    float c = cr[j], s = sr[j];
                    float v1 = acc[mi][nj][r], v2 = acc[mi][nj + 2][r];
                    ob[j] = b2s((v1 * c - v2 * s) * sc);
                    ob[j + 32] = b2s((v2 * c + v1 * s) * sc);
                }
            }
    } else {  // EPI == 2: V^T layout [B,H,64,n]
        const int hh = n0 >> 6;
        unsigned short* out = (unsigned short*)Cv;
#pragma unroll
        for (int mi = 0; mi < 2; ++mi)
#pragma unroll
            for (int nj = 0; nj < 4; ++nj) {
                int d = nj * 16 + l16;
                int row0 = m0 + w * 32 + mi * 16 + g * 4;
                int b = row0 >> 11, pos0 = row0 & (NTOK - 1);
                short4v o;
#pragma unroll
                for (int r = 0; r < 4; ++r) o[r] = (short)b2s(acc[mi][nj][r]);
                *(short4v*)(out + (size_t)((b * HH + hh) * DH + d) * NTOK + pos0) = o;
            }
    }
}

// ---- fused masked flash attention v4: 8 waves / 512 thr, wave owns 16 q-rows ----
// grid 512 = (b,h,ti) with bijective XCD chunk swizzle (64 blocks/XCD = 2MB K/V, L2-fit).
// K LDS-staged via global_load_lds (dbuf, frag order, conflict-free); V reg-staged ->
// LDS in P-matching frag order (kv slots {g*4+r, 16+g*4+r}); S^T=K@Q^T, O^T=V^T@P^T.
__global__ __launch_bounds__(512, 4) void k_attn(const unsigned short* __restrict__ qh,
                                                 const unsigned short* __restrict__ kh,
                                                 const unsigned short* __restrict__ vt,
                                                 const int* __restrict__ tmask,
                                                 unsigned short* __restrict__ otmp) {
    __shared__ unsigned short Kb[2][8192];  // 16 frags x 512 shorts
    __shared__ unsigned short Vb[8192];
    __shared__ int tlist[17];
    const int blk = blockIdx.x;
    const int u = (blk & 7) * 64 + (blk >> 3);  // bijective XCD chunking (512 % 8 == 0)
    const int ti = u & 15, h = (u >> 4) & 15, b = u >> 8;
    const int tid = threadIdx.x, w = tid >> 6, l = tid & 63, l16 = l & 15, g = l >> 4;
    if (tid == 0) {
        int c = 0;
        for (int j = 0; j < 16; ++j)
            if (tmask[(b * 16 + ti) * 16 + j]) tlist[c++] = j;
        tlist[16] = c;
    }
    __syncthreads();
    const int cnt = tlist[16];
    const unsigned short* qb = qh + (size_t)((b * HH + h) * NTOK) * DH;
    const unsigned short* kb = kh + (size_t)((b * HH + h) * NTOK) * DH;
    const unsigned short* vb = vt + (size_t)((b * HH + h) * DH) * NTOK;
    const int q0 = ti * 128 + w * 16;

    short8v qf[2];
#pragma unroll
    for (int c = 0; c < 2; ++c)
        qf[c] = *(const short8v*)(qb + (size_t)(q0 + l16) * DH + c * 32 + g * 8);

    float4v oacc[4];
#pragma unroll
    for (int i = 0; i < 4; ++i) oacc[i] = (float4v){0.f, 0.f, 0.f, 0.f};
    float mx = -1e30f, lrow = 0.f;
    uint4v vrg[2];

    auto stageK = [&](int tj, int buf) {
#pragma unroll
        for (int s = 0; s < 2; ++s) {
            int fi = w * 2 + s;  // frag (jk = fi>>1, c = fi&1)
            const unsigned short* ga =
                kb + (size_t)(tj * 128 + (fi >> 1) * 16 + l16) * DH + (fi & 1) * 32 + g * 8;
            gld16(ga, &Kb[buf][fi * 512]);
        }
    };
    auto loadV = [&](int tj) {
#pragma unroll
        for (int s = 0; s < 2; ++s) {
            int fi = w * 2 + s;  // md = fi>>2, cc = fi&3
            const unsigned short* ga =
                vb + (size_t)((fi >> 2) * 16 + l16) * NTOK + tj * 128 + (fi & 3) * 32 + g * 4;
            uint2v lo = *(const uint2v*)ga;
            uint2v hi = *(const uint2v*)(ga + 16);
            vrg[s] = (uint4v){lo[0], lo[1], hi[0], hi[1]};
        }
    };
    auto writeV = [&]() {
#pragma unroll
        for (int s = 0; s < 2; ++s)
            *(uint4v*)&Vb[(w * 2 + s) * 512 + l * 8] = vrg[s];
    };

    if (cnt > 0) {
        stageK(tlist[0], 0);
        loadV(tlist[0]);
        writeV();
        __syncthreads();
        for (int i = 0; i < cnt; ++i) {
            const int cur = i & 1;
            const bool pre = (i + 1 < cnt);
            if (pre) { stageK(tlist[i + 1], cur ^ 1); loadV(tlist[i + 1]); }
            // ---- QK^T ----
            float4v sacc[8];
#pragma unroll
            for (int jk = 0; jk < 8; ++jk) sacc[jk] = (float4v){0.f, 0.f, 0.f, 0.f};
            __builtin_amdgcn_s_setprio(1);
#pragma unroll
            for (int jk = 0; jk < 8; ++jk) {
                short8v kf0 = *(const short8v*)&Kb[cur][(jk * 2 + 0) * 512 + l * 8];
                short8v kf1 = *(const short8v*)&Kb[cur][(jk * 2 + 1) * 512 + l * 8];
                sacc[jk] = mfma32(kf0, qf[0], sacc[jk]);
                sacc[jk] = mfma32(kf1, qf[1], sacc[jk]);
            }
            __builtin_amdgcn_s_setprio(0);
            // ---- online softmax (base-2; log2e folded into q) with defer-max ----
            float tm = -1e30f;
#pragma unroll
            for (int jk = 0; jk < 8; ++jk) {
                float4v s4 = sacc[jk];
                tm = fmaxf(tm, fmaxf(fmaxf(s4[0], s4[1]), fmaxf(s4[2], s4[3])));
            }
            tm = fmaxf(tm, __shfl_xor(tm, 16));
            tm = fmaxf(tm, __shfl_xor(tm, 32));
            if (!__all(tm <= mx + 8.0f)) {  // defer-max: p bounded by 2^8
                float mnew = fmaxf(mx, tm);
                float alpha = exp2f(mx - mnew);
                lrow *= alpha;
#pragma unroll
                for (int md = 0; md < 4; ++md)
#pragma unroll
                    for (int r = 0; r < 4; ++r) oacc[md][r] *= alpha;
                mx = mnew;
            }
            short8v pf[4];
            float4v tsv = {0.f, 0.f, 0.f, 0.f};
#pragma unroll
            for (int cc = 0; cc < 4; ++cc) {
                float p[8];
#pragma unroll
                for (int r = 0; r < 4; ++r) {
                    p[r] = exp2f(sacc[2 * cc][r] - mx);
                    p[r + 4] = exp2f(sacc[2 * cc + 1][r] - mx);
                }
                short8v pv;
#pragma unroll
                for (int r = 0; r < 4; ++r) {
                    tsv[r] += p[r] + p[r + 4];
                    pv[r] = (short)b2s(p[r]);
                    pv[r + 4] = (short)b2s(p[r + 4]);
                }
                pf[cc] = pv;
            }
            float ts = (tsv[0] + tsv[1]) + (tsv[2] + tsv[3]);
            ts += __shfl_xor(ts, 16);
            ts += __shfl_xor(ts, 32);
            lrow += ts;
            // ---- O^T += V^T @ P^T ----
            __builtin_amdgcn_s_setprio(1);
#pragma unroll
            for (int md = 0; md < 4; ++md)
#pragma unroll
                for (int cc = 0; cc < 4; ++cc) {
                    short8v vf = *(const short8v*)&Vb[(md * 4 + cc) * 512 + l * 8];
                    oacc[md] = mfma32(vf, pf[cc], oacc[md]);
                }
            __builtin_amdgcn_s_setprio(0);
            __syncthreads();  // all waves done with Vb + staged loads drained
            if (pre) writeV();
            __syncthreads();
        }
    }
    float inv = lrow > 0.f ? 1.0f / lrow : 0.f;
    int q = q0 + l16;
#pragma unroll
    for (int md = 0; md < 4; ++md) {
        short4v o;
#pragma unroll
        for (int r = 0; r < 4; ++r) o[r] = (short)b2s(oacc[md][r] * inv);
        *(short4v*)(otmp + (size_t)(b * NTOK + q) * NINNER + h * DH + md * 16 + g * 4) = o;
    }
}

// ---- gate: out = proj * sigmoid(proj @ gate_w + gate_b) ----
__global__ __launch_bounds__(256) void k_gate(const float* __restrict__ proj,
                                              const float* __restrict__ gw,
                                              const float* __restrict__ gb,
                                              float* __restrict__ out) {
    int row = blockIdx.x * 4 + (threadIdx.x >> 6);
    int l = threadIdx.x & 63;
    const float* pr = proj + (size_t)row * DMODEL;
    float acc = 0.f;
#pragma unroll
    for (int c = 0; c < DMODEL; c += 64) acc += pr[c + l] * gw[c + l];
#pragma unroll
    for (int off = 32; off > 0; off >>= 1) acc += __shfl_xor(acc, off);
    float gt = 1.0f / (1.0f + __expf(-(acc + gb[0])));
    float* orow = out + (size_t)row * DMODEL;
#pragma unroll
    for (int c = 0; c < DMODEL; c += 64) orow[c + l] = pr[c + l] * gt;
}

extern "C" void kernel_launch(void* const* d_in, const int* in_sizes, int n_in,
                              void* d_out, int out_size, void* d_ws, size_t ws_size,
                              hipStream_t stream) {
    (void)in_sizes; (void)n_in; (void)out_size; (void)ws_size;
    const float* x = (const float*)d_in[0];
    const float* y = (const float*)d_in[1];
    const int* tmask = (const int*)d_in[2];
    const float* Wq = (const float*)d_in[3];
    const float* Wk = (const float*)d_in[4];
    const float* Wv = (const float*)d_in[5];
    const float* Wo = (const float*)d_in[6];
    const float* bo = (const float*)d_in[7];
    const float* pe = (const float*)d_in[8];
    const float* gw = (const float*)d_in[9];
    const float* gb = (const float*)d_in[10];

    char* ws = (char*)d_ws;
    const size_t MB = 1u << 20;
    unsigned short* xpb  = (unsigned short*)(ws + 0);         // 4MB
    unsigned short* ypb  = (unsigned short*)(ws + 4 * MB);    // 4MB
    unsigned short* wqkt = (unsigned short*)(ws + 8 * MB);    // 2MB [2048][512] (q rows 0..1023, k rows 1024..2047)
    unsigned short* wvt  = (unsigned short*)(ws + 10 * MB);   // 1MB
    unsigned short* wot  = (unsigned short*)(ws + 11 * MB);   // 1MB
    unsigned short* qh   = (unsigned short*)(ws + 12 * MB);   // 8MB  [B,H,n,64] bf16
    unsigned short* kh   = (unsigned short*)(ws + 20 * MB);   // 8MB
    unsigned short* vt   = (unsigned short*)(ws + 28 * MB);   // 8MB  [B,H,64,n] bf16
    unsigned short* otm  = (unsigned short*)(ws + 36 * MB);   // 8MB  [B*n,1024] bf16
    float* proj = (float*)(ws + 44 * MB);                     // 8MB  f32
    float* ct = (float*)(ws + 52 * MB);                       // 256KB
    float* st = (float*)(ws + 52 * MB + 256 * 1024);          // 256KB
    float* outp = (float*)d_out;

    k_pre<<<10496, 256, 0, stream>>>(x, y, pe, xpb, ypb, Wq, Wk, Wv, Wo,
                                     wqkt, wvt, wot, ct, st);
    // q,k from x (bug-compatible with reference); v from y.
    k_gemm<1><<<dim3(32, 32), 256, 0, stream>>>(xpb, wqkt, qh, kh, nullptr, ct, st,
                                                0.125f * LOG2E, 4096, 2048, 512);
    k_gemm<2><<<dim3(16, 32), 256, 0, stream>>>(ypb, wvt, vt, nullptr, nullptr, nullptr,
                                                nullptr, 1.0f, 4096, 1024, 512);
    k_attn<<<512, 512, 0, stream>>>(qh, kh, vt, tmask, otm);
    k_gemm<0><<<dim3(8, 32), 256, 0, stream>>>(otm, wot, proj, nullptr, bo, nullptr,
                                               nullptr, 1.0f, 4096, 512, 1024);
    k_gate<<<1024, 256, 0, stream>>>(proj, gw, gb, outp);
}